// Round 19
// baseline (283.136 us; speedup 1.0000x reference)
//
#include <hip/hip_runtime.h>
#include <hip/hip_bf16.h>

typedef unsigned short u16;
typedef __attribute__((ext_vector_type(8))) short short8;
typedef __attribute__((ext_vector_type(8))) unsigned short ushort8;
typedef __attribute__((ext_vector_type(4))) float f32x4;
typedef __attribute__((ext_vector_type(4))) float f4;

#define GLB_CAST(p) ((const __attribute__((address_space(1))) unsigned int*)(p))
#define LDS_CAST(p) ((__attribute__((address_space(3))) unsigned int*)(p))

__device__ __forceinline__ void gl_lds16(const void* g, void* l) {
  __builtin_amdgcn_global_load_lds(GLB_CAST(g), LDS_CAST(l), 16, 0, 0);
}

__device__ __forceinline__ u16 f2bf(float f) {
  __hip_bfloat16 b = __float2bfloat16(f);           // RNE
  return __builtin_bit_cast(u16, b);
}
__device__ __forceinline__ float bf2f(u16 u) {
  unsigned int x = ((unsigned int)u) << 16;
  return __builtin_bit_cast(float, x);
}

// ---------------- prep: W [R][C] f32 -> Wt [C][R] bf16 ----------------
__global__ void transpose_cvt_k(const float* __restrict__ in,
                                u16* __restrict__ out, int R, int C) {
  __shared__ float tile[32][33];
  int c0 = blockIdx.x * 32, r0 = blockIdx.y * 32;
  int tx = threadIdx.x, ty = threadIdx.y;     // 32 x 8
#pragma unroll
  for (int i = 0; i < 32; i += 8)
    tile[ty + i][tx] = in[(size_t)(r0 + ty + i) * C + c0 + tx];
  __syncthreads();
#pragma unroll
  for (int i = 0; i < 32; i += 8)
    out[(size_t)(c0 + ty + i) * R + r0 + tx] = f2bf(tile[tx][ty + i]);
}

// ========== R19 GEMM: 32-row A-tile, 3 blocks/CU (12 waves/CU), barrier-free ==========
// Block 256 thr = 4 waves; wave owns 32 n-cols; A [32x384] resident LDS (24KB);
// per-wave-private B ring (3 x 2KB), depth-2 prefetch, counted vmcnt, no loop barriers.
// NT loads keep the A read-stream out of L2 (B panel survives, R15/R16-proven);
// scattered-store epilogue (no repack buffer) to fit 51.5KB -> 3 blocks/CU.
// EPI=1: qkv -> q/k row-major [b,h,t,d] + vT [b,h,d,t] (bf16); NT=9.
// EPI=2: out = att@pT^T + bias -> f32 [M,384] via NT stores; NT=3.
template <int EPI>
__global__ __launch_bounds__(256, 3) void gemm_k(
    const void* __restrict__ Av, const u16* __restrict__ Bt,
    const float* __restrict__ bias,
    u16* __restrict__ oQ, u16* __restrict__ oK, u16* __restrict__ oVT,
    float* __restrict__ oF) {
  constexpr int K = 384;
  constexpr int NT = (EPI == 1) ? 9 : 3;
  __shared__ u16 As[32 * 384];         // 24KB, swizzled rows of 768B
  __shared__ u16 Bs[4][3][1024];       // 24KB: per-wave 3 slots [32col][32k]
  __shared__ u16 bias_sh[NT * 128];    // bf16 bias

  const int tid = threadIdx.x;
  const int m0 = blockIdx.x * 32;
  const int lane = tid & 63, wid = tid >> 6;   // wid = wc (4 waves x 32 cols)
  const int lo = lane & 15, hi = lane >> 4;
  const int wc = wid;

  for (int i = tid; i < NT * 128; i += 256) bias_sh[i] = f2bf(bias[i]);

  // ---- B staging (CACHEABLE - must stay L2-resident) ----
  const int bcol = wc * 32 + (lane >> 2);
  const int bc = ((lane & 3) ^ ((lane >> 3) & 3)) * 8;   // source k-offset (elems)
  char* const slot_l = (char*)&Bs[0][0][0] + wid * 6144 + lane * 16;
  auto stageB = [&](int slot, int tn, int kt) {
    const u16* s = Bt + (size_t)(tn * 128 + bcol) * K + kt * 32 + bc;
    char* d = slot_l + slot * 2048;
    gl_lds16(s, d);
    gl_lds16(s + 16 * K, d + 1024);
  };

  stageB(0, 0, 0);
  stageB(1, 0, 1);

  // ---- A staged once (NON-TEMPORAL loads: stream must not evict B) ----
  if (EPI == 1) {
    const float* X = (const float*)Av;
#pragma unroll
    for (int i = 0; i < 6; ++i) {
      int c = tid + i * 256;           // 1536 chunks of 16B
      int row = c / 48, cc = c % 48;
      const float* src = X + (size_t)(m0 + row) * K + cc * 8;
      f4 a = __builtin_nontemporal_load((const f4*)src);
      f4 b = __builtin_nontemporal_load((const f4*)(src + 4));
      ushort8 o;
#pragma unroll
      for (int j = 0; j < 4; ++j) { o[j] = f2bf(a[j]); o[4 + j] = f2bf(b[j]); }
      *(ushort8*)((char*)As + row * 768 + ((cc * 16) ^ ((row & 7) << 4))) = o;
    }
  } else {
    const u16* Ab = (const u16*)Av;
#pragma unroll
    for (int i = 0; i < 6; ++i) {
      int c = tid + i * 256;
      int row = c / 48, cc = c % 48;
      ushort8 v = __builtin_nontemporal_load(
          (const ushort8*)(Ab + (size_t)(m0 + row) * K + cc * 8));
      *(ushort8*)((char*)As + row * 768 + ((cc * 16) ^ ((row & 7) << 4))) = v;
    }
  }
  __syncthreads();    // full drain (A ready, prologue B slots 0/1 ready)

  const int akey = (lo & 7) << 4;
  const int rk = ((lo >> 1) & 3) << 4;       // B read key
  int abase[2];
#pragma unroll
  for (int m = 0; m < 2; ++m) abase[m] = (m * 16 + lo) * 768;
  const int bbase = lo * 64 + (hi * 16 ^ rk);
  const char* const Asc = (const char*)As;
  const char* const sb0 = (const char*)&Bs[0][0][0] + wid * 6144;

  // hoisted epilogue row parts (gm = m0 + m*16 + hi*4 + rr)
  int rqk[2][4], rv[2][4];
#pragma unroll
  for (int m = 0; m < 2; ++m)
#pragma unroll
    for (int rr = 0; rr < 4; ++rr) {
      int gm = m0 + m * 16 + hi * 4 + rr;
      int b = gm >> 8, tt = gm & 255;
      rqk[m][rr] = b * 98304 + tt * 64;     // q/k: b*6*16384 + t*64
      rv[m][rr] = b * 98304 + tt;           // vT:  b*6*16384 + t
    }

  const f32x4 Z4 = {0.f, 0.f, 0.f, 0.f};

  for (int t = 0; t < NT; ++t) {
    f32x4 acc[2][2];
#pragma unroll
    for (int m = 0; m < 2; ++m) { acc[m][0] = Z4; acc[m][1] = Z4; }

#pragma unroll
    for (int kt = 0; kt < 12; ++kt) {
      // per-wave counted wait: slot(kt) ready, depth-2 pipeline stays live.
      // kt==0 also retires prev tile's 16 epilogue stores (in-order vmcnt).
      if (kt == 0) asm volatile("s_waitcnt vmcnt(4)" ::: "memory");
      else         asm volatile("s_waitcnt vmcnt(2)" ::: "memory");

      const char* sb = sb0 + (kt % 3) * 2048;
      short8 af[2], bf[2];
#pragma unroll
      for (int m = 0; m < 2; ++m)
        af[m] = *(const short8*)(Asc + abase[m] + ((kt * 64 + hi * 16) ^ akey));
      bf[0] = *(const short8*)(sb + bbase);
      bf[1] = *(const short8*)(sb + 1024 + bbase);

      if (kt < 10)           stageB((kt + 2) % 3, t, kt + 2);
      else if (t + 1 < NT)   stageB((kt + 2) % 3, t + 1, kt - 10);

      __builtin_amdgcn_s_setprio(1);
#pragma unroll
      for (int m = 0; m < 2; ++m) {
        acc[m][0] = __builtin_amdgcn_mfma_f32_16x16x32_bf16(af[m], bf[0], acc[m][0], 0, 0, 0);
        acc[m][1] = __builtin_amdgcn_mfma_f32_16x16x32_bf16(af[m], bf[1], acc[m][1], 0, 0, 0);
      }
      __builtin_amdgcn_s_setprio(0);
    }

    // ---- epilogue: direct stores (fire-and-forget; retired by next kt=0 wait) ----
    float bs0 = bf2f(bias_sh[t * 128 + wc * 32 + lo]);
    float bs1 = bf2f(bias_sh[t * 128 + wc * 32 + 16 + lo]);

    if (EPI == 1) {
      const int r3 = t / 3;
      u16* dst = (r3 == 0) ? oQ : ((r3 == 1) ? oK : oVT);
      const int hcb = (t - r3 * 3) * 128 + wc * 32 + lo;
#pragma unroll
      for (int n = 0; n < 2; ++n) {
        int hc = hcb + n * 16;
        float bs = n ? bs1 : bs0;
        int cp = (r3 < 2) ? (((hc >> 6) << 14) + (hc & 63))
                          : (((hc >> 6) << 14) + (hc & 63) * 256);
        const int (*rp)[4] = (r3 < 2) ? rqk : rv;
#pragma unroll
        for (int m = 0; m < 2; ++m)
#pragma unroll
          for (int rr = 0; rr < 4; ++rr)
            dst[(size_t)(rp[m][rr] + cp)] = f2bf(acc[m][n][rr] + bs);
      }
    } else {
      const int colb = t * 128 + wc * 32 + lo;
#pragma unroll
      for (int m = 0; m < 2; ++m)
#pragma unroll
        for (int rr = 0; rr < 4; ++rr) {
          int gm = m0 + m * 16 + hi * 4 + rr;
          __builtin_nontemporal_store(acc[m][0][rr] + bs0, &oF[(size_t)gm * 384 + colb]);
          __builtin_nontemporal_store(acc[m][1][rr] + bs1, &oF[(size_t)gm * 384 + colb + 16]);
        }
    }
  }
}

// ---------------- windowed causal attention (K and V^T staged via gl_lds) ----------------
__global__ __launch_bounds__(256) void attn_k(
    const u16* __restrict__ Qb, const u16* __restrict__ Kb,
    const u16* __restrict__ VTb, const float* __restrict__ gate,
    u16* __restrict__ Ao) {
  __shared__ u16 Ks[128 * 64];      // [key][d]   swizzled, 16KB
  __shared__ u16 Vs[64 * 128];      // [d][key]   swizzled, 16KB
  __shared__ u16 Ps[4][16 * 128];   // per-wave P [q][key] swizzled, 16KB
  const int bx = blockIdx.x;
  const int qt = bx & 3, bh = bx >> 2;
  const int h = bh % 6, b = bh / 6;
  const int i0 = qt * 64, j0 = i0 - 64;
  const int tid = threadIdx.x, w = tid >> 6, lane = tid & 63;
  const int lo = lane & 15, hi = lane >> 4;

  const u16* Kh = Kb + (size_t)bh * (256 * 64);
  const u16* Vh = VTb + (size_t)bh * (64 * 256);
  const u16* Qh = Qb + (size_t)bh * (256 * 64);

#pragma unroll
  for (int it = 0; it < 4; ++it) {
    int chunk = tid + it * 256;
    int row = chunk >> 3, cc = chunk & 7;
    int csrc = cc ^ (row & 7);
    int j = j0 + row; if (j < 0) j = 0;       // masked later via P=0
    gl_lds16(Kh + j * 64 + csrc * 8, Ks + chunk * 8);
  }
#pragma unroll
  for (int it = 0; it < 4; ++it) {
    int chunk = tid + it * 256;
    int d = chunk >> 4, kc = chunk & 15;
    int ksrc = kc ^ (d & 7);
    int j = j0 + ksrc * 8; if (j < 0) j = 0;  // whole-chunk invalid only
    gl_lds16(Vh + d * 256 + j, Vs + chunk * 8);
  }

  const int iq = i0 + w * 16 + lo;
  short8 aq0 = *(const short8*)(Qh + iq * 64 + hi * 8);
  short8 aq1 = *(const short8*)(Qh + iq * 64 + 32 + hi * 8);

  __syncthreads();

  const f32x4 Z4 = {0.f, 0.f, 0.f, 0.f};
  f32x4 accS[8];
#pragma unroll
  for (int t = 0; t < 8; ++t) accS[t] = Z4;
#pragma unroll
  for (int t = 0; t < 8; ++t) {
    int key = t * 16 + lo;
    int base = key * 128;
    int sw = (key & 7) << 4;
    short8 bk0 = *(const short8*)((const char*)Ks + ((base + hi * 16) ^ sw));
    short8 bk1 = *(const short8*)((const char*)Ks + ((base + 64 + hi * 16) ^ sw));
    accS[t] = __builtin_amdgcn_mfma_f32_16x16x32_bf16(aq0, bk0, accS[t], 0, 0, 0);
    accS[t] = __builtin_amdgcn_mfma_f32_16x16x32_bf16(aq1, bk1, accS[t], 0, 0, 0);
  }

  float pv[4][8];
  float rinv[4];
#pragma unroll
  for (int r = 0; r < 4; ++r) {
    int i = i0 + w * 16 + hi * 4 + r;
    float mx = -1e30f;
    float vals[8];
#pragma unroll
    for (int t = 0; t < 8; ++t) {
      int j = j0 + t * 16 + lo;
      float s = accS[t][r] * 0.125f;          // 1/sqrt(64)
      bool ok = (j >= 0) && (j <= i) && (j >= i - 64);
      vals[t] = ok ? s : -1e30f;
      mx = fmaxf(mx, vals[t]);
    }
#pragma unroll
    for (int off = 1; off < 16; off <<= 1) mx = fmaxf(mx, __shfl_xor(mx, off));
    float sum = 0.f;
#pragma unroll
    for (int t = 0; t < 8; ++t) {
      float p = __expf(vals[t] - mx);
      pv[r][t] = p;
      sum += p;
    }
#pragma unroll
    for (int off = 1; off < 16; off <<= 1) sum += __shfl_xor(sum, off);
    rinv[r] = 1.0f / sum;
  }

  u16* Pw = Ps[w];
#pragma unroll
  for (int r = 0; r < 4; ++r) {
    int ql = hi * 4 + r;
    int sw = (ql & 7) << 4;
#pragma unroll
    for (int t = 0; t < 8; ++t) {
      int off = (ql * 256 + (t * 16 + lo) * 2) ^ sw;
      *(u16*)((char*)Pw + off) = f2bf(pv[r][t]);
    }
  }

  f32x4 accO[4];
#pragma unroll
  for (int dt = 0; dt < 4; ++dt) accO[dt] = Z4;
#pragma unroll
  for (int ks = 0; ks < 4; ++ks) {
    int offA = (lo * 256 + ks * 64 + hi * 16) ^ ((lo & 7) << 4);
    short8 ap = *(const short8*)((const char*)Pw + offA);
#pragma unroll
    for (int dt = 0; dt < 4; ++dt) {
      int d = dt * 16 + lo;
      int offB = (d * 256 + ks * 64 + hi * 16) ^ ((d & 7) << 4);
      short8 bv = *(const short8*)((const char*)Vs + offB);
      accO[dt] = __builtin_amdgcn_mfma_f32_16x16x32_bf16(ap, bv, accO[dt], 0, 0, 0);
    }
  }

#pragma unroll
  for (int dt = 0; dt < 4; ++dt) {
    int d = dt * 16 + lo;
    float gg = gate[h * 64 + d];
#pragma unroll
    for (int r = 0; r < 4; ++r) {
      int i = i0 + w * 16 + hi * 4 + r;
      float v = accO[dt][r] * rinv[r] * gg;
      Ao[(size_t)(b * 256 + i) * 384 + h * 64 + d] = f2bf(v);
    }
  }
}

// ---------------- launch ----------------
extern "C" void kernel_launch(void* const* d_in, const int* in_sizes, int n_in,
                              void* d_out, int out_size, void* d_ws, size_t ws_size,
                              hipStream_t stream) {
  const float* x      = (const float*)d_in[0];
  const float* qkv_w  = (const float*)d_in[1];
  const float* qkv_b  = (const float*)d_in[2];
  const float* proj_w = (const float*)d_in[3];
  const float* proj_b = (const float*)d_in[4];
  const float* gate   = (const float*)d_in[5];
  float* out = (float*)d_out;

  // ws layout:
  //   [0, 50331648)            att (attention output, bf16)
  //   [50331648, 100663296)    vT [b,h,d,t] bf16
  //   [100663296, 101548032)   w1T [1152,384] bf16
  //   [101548032, 101842944)   pT  [384,384]  bf16
  char* ws = (char*)d_ws;
  u16* att  = (u16*)ws;
  u16* vT   = (u16*)(ws + 50331648);
  u16* w1T  = (u16*)(ws + 100663296);
  u16* pT   = (u16*)(ws + 101548032);
  u16* qbuf = (u16*)d_out;                         // d_out doubles as q+k scratch
  u16* kbuf = (u16*)((char*)d_out + 50331648);

  transpose_cvt_k<<<dim3(36, 12), dim3(32, 8), 0, stream>>>(qkv_w, w1T, 384, 1152);
  transpose_cvt_k<<<dim3(12, 12), dim3(32, 8), 0, stream>>>(proj_w, pT, 384, 384);

  gemm_k<1><<<2048, 256, 0, stream>>>(x, w1T, qkv_b, qbuf, kbuf, vT, nullptr);
  attn_k<<<256 * 6 * 4, 256, 0, stream>>>(qbuf, kbuf, vT, gate, att);
  gemm_k<2><<<2048, 256, 0, stream>>>(att, pT, proj_b, nullptr, nullptr, nullptr, out);
}

// Round 20
// 188.086 us; speedup vs baseline: 1.5053x; 1.5053x over previous
//
#include <hip/hip_runtime.h>
#include <hip/hip_bf16.h>

typedef unsigned short u16;
typedef __attribute__((ext_vector_type(8))) short short8;
typedef __attribute__((ext_vector_type(8))) unsigned short ushort8;
typedef __attribute__((ext_vector_type(4))) float f32x4;
typedef __attribute__((ext_vector_type(4))) float f4;

#define GLB_CAST(p) ((const __attribute__((address_space(1))) unsigned int*)(p))
#define LDS_CAST(p) ((__attribute__((address_space(3))) unsigned int*)(p))

__device__ __forceinline__ void gl_lds16(const void* g, void* l) {
  __builtin_amdgcn_global_load_lds(GLB_CAST(g), LDS_CAST(l), 16, 0, 0);
}

__device__ __forceinline__ u16 f2bf(float f) {
  __hip_bfloat16 b = __float2bfloat16(f);           // RNE
  return __builtin_bit_cast(u16, b);
}
__device__ __forceinline__ float bf2f(u16 u) {
  unsigned int x = ((unsigned int)u) << 16;
  return __builtin_bit_cast(float, x);
}

// ---------------- prep: W [R][C] f32 -> Wt [C][R] bf16 ----------------
__global__ void transpose_cvt_k(const float* __restrict__ in,
                                u16* __restrict__ out, int R, int C) {
  __shared__ float tile[32][33];
  int c0 = blockIdx.x * 32, r0 = blockIdx.y * 32;
  int tx = threadIdx.x, ty = threadIdx.y;     // 32 x 8
#pragma unroll
  for (int i = 0; i < 32; i += 8)
    tile[ty + i][tx] = in[(size_t)(r0 + ty + i) * C + c0 + tx];
  __syncthreads();
#pragma unroll
  for (int i = 0; i < 32; i += 8)
    out[(size_t)(c0 + ty + i) * R + r0 + tx] = f2bf(tile[tx][ty + i]);
}

// ========== R16 GEMM: NT A-stream loads; CACHED q/k/vT stores; NT final-out ==========
// Block 256 thr = 4 waves; wave owns 32 n-cols; A [64x384] resident LDS (48KB);
// per-wave-private B ring (3 x 2KB), depth-2 prefetch, counted vmcnt, no loop barriers.
// NT loads keep the 48MB read-stream out of L2 (B panel survives); q/k/vT stores
// CACHED (attn consumes them soon -> L2/L3 hits, stores write-combine); gemm2's
// final f32 out stays NT (full-line, never re-read on device).
// EPI=1: qkv -> q/k row-major [b,h,t,d] + vT [b,h,d,t] (bf16); NT=9.
// EPI=2: out = att@pT^T + bias -> f32 [M,384]; NT=3.
template <int EPI>
__global__ __launch_bounds__(256, 2) void gemm_k(
    const void* __restrict__ Av, const u16* __restrict__ Bt,
    const float* __restrict__ bias,
    u16* __restrict__ oQ, u16* __restrict__ oK, u16* __restrict__ oVT,
    float* __restrict__ oF) {
  constexpr int K = 384;
  constexpr int NT = (EPI == 1) ? 9 : 3;
  __shared__ u16 As[64 * 384];         // 48KB, swizzled rows of 768B
  __shared__ u16 Bs[4][3][1024];       // 24KB: per-wave 3 slots [32col][32k]
  __shared__ u16 Rs[4][512];           // 4KB: per-wave 1KB repack chunk
  __shared__ u16 bias_sh[NT * 128];    // bf16 bias

  const int tid = threadIdx.x;
  const int m0 = blockIdx.x * 64;
  const int lane = tid & 63, wid = tid >> 6;   // wid = wc (4 waves x 32 cols)
  const int lo = lane & 15, hi = lane >> 4;
  const int wc = wid;

  for (int i = tid; i < NT * 128; i += 256) bias_sh[i] = f2bf(bias[i]);

  // ---- B staging (CACHEABLE - must stay L2-resident) ----
  const int bcol = wc * 32 + (lane >> 2);
  const int bc = ((lane & 3) ^ ((lane >> 3) & 3)) * 8;   // source k-offset (elems)
  char* const slot_l = (char*)&Bs[0][0][0] + wid * 6144 + lane * 16;
  auto stageB = [&](int slot, int tn, int kt) {
    const u16* s = Bt + (size_t)(tn * 128 + bcol) * K + kt * 32 + bc;
    char* d = slot_l + slot * 2048;
    gl_lds16(s, d);
    gl_lds16(s + 16 * K, d + 1024);
  };

  stageB(0, 0, 0);
  stageB(1, 0, 1);

  // ---- A staged once (NON-TEMPORAL loads: stream must not evict B) ----
  if (EPI == 1) {
    const float* X = (const float*)Av;
#pragma unroll
    for (int i = 0; i < 12; ++i) {
      int c = tid + i * 256;           // 3072 chunks of 16B
      int row = c / 48, cc = c % 48;
      const float* src = X + (size_t)(m0 + row) * K + cc * 8;
      f4 a = __builtin_nontemporal_load((const f4*)src);
      f4 b = __builtin_nontemporal_load((const f4*)(src + 4));
      ushort8 o;
#pragma unroll
      for (int j = 0; j < 4; ++j) { o[j] = f2bf(a[j]); o[4 + j] = f2bf(b[j]); }
      *(ushort8*)((char*)As + row * 768 + ((cc * 16) ^ ((row & 7) << 4))) = o;
    }
  } else {
    const u16* Ab = (const u16*)Av;
#pragma unroll
    for (int i = 0; i < 12; ++i) {
      int c = tid + i * 256;
      int row = c / 48, cc = c % 48;
      ushort8 v = __builtin_nontemporal_load(
          (const ushort8*)(Ab + (size_t)(m0 + row) * K + cc * 8));
      *(ushort8*)((char*)As + row * 768 + ((cc * 16) ^ ((row & 7) << 4))) = v;
    }
  }
  __syncthreads();    // full drain (A ready, prologue B slots 0/1 ready)

  const int akey = (lo & 7) << 4;
  const int rk = ((lo >> 1) & 3) << 4;       // B read key
  int abase[4];
#pragma unroll
  for (int m = 0; m < 4; ++m) abase[m] = (m * 16 + lo) * 768;
  const int bbase = lo * 64 + (hi * 16 ^ rk);
  const char* const Asc = (const char*)As;
  const char* const sb0 = (const char*)&Bs[0][0][0] + wid * 6144;
  char* const rp_ = (char*)&Rs[0][0] + wid * 1024;

  const f32x4 Z4 = {0.f, 0.f, 0.f, 0.f};

  for (int t = 0; t < NT; ++t) {
    f32x4 acc[4][2];
#pragma unroll
    for (int m = 0; m < 4; ++m) { acc[m][0] = Z4; acc[m][1] = Z4; }

#pragma unroll
    for (int kt = 0; kt < 12; ++kt) {
      // per-wave counted wait: slot(kt) ready, depth-2 pipeline stays live.
      if (kt == 0) asm volatile("s_waitcnt vmcnt(4)" ::: "memory");
      else         asm volatile("s_waitcnt vmcnt(2)" ::: "memory");

      const char* sb = sb0 + (kt % 3) * 2048;
      short8 af[4], bf[2];
#pragma unroll
      for (int m = 0; m < 4; ++m)
        af[m] = *(const short8*)(Asc + abase[m] + ((kt * 64 + hi * 16) ^ akey));
      bf[0] = *(const short8*)(sb + bbase);
      bf[1] = *(const short8*)(sb + 1024 + bbase);

      if (kt < 10)           stageB((kt + 2) % 3, t, kt + 2);
      else if (t + 1 < NT)   stageB((kt + 2) % 3, t + 1, kt - 10);

      __builtin_amdgcn_s_setprio(1);
#pragma unroll
      for (int m = 0; m < 4; ++m) {
        acc[m][0] = __builtin_amdgcn_mfma_f32_16x16x32_bf16(af[m], bf[0], acc[m][0], 0, 0, 0);
        acc[m][1] = __builtin_amdgcn_mfma_f32_16x16x32_bf16(af[m], bf[1], acc[m][1], 0, 0, 0);
      }
      __builtin_amdgcn_s_setprio(0);
    }

    // ---- epilogue: wave-private LDS repack -> coalesced CACHED 16B stores ----
    float bs0 = bf2f(bias_sh[t * 128 + wc * 32 + lo]);
    float bs1 = bf2f(bias_sh[t * 128 + wc * 32 + 16 + lo]);

    if (EPI == 1) {
      const int r3 = t / 3;
      u16* dst = (r3 == 0) ? oQ : ((r3 == 1) ? oK : oVT);
      const int hcb = (t - r3 * 3) * 128 + wc * 32;     // wave's head-space col base
      if (r3 < 2) {
        // chunk [16m][32col], 64B rows
#pragma unroll
        for (int p = 0; p < 4; ++p) {
#pragma unroll
          for (int n = 0; n < 2; ++n)
#pragma unroll
            for (int rr = 0; rr < 4; ++rr)
              *(u16*)(rp_ + (hi * 4 + rr) * 64 + (n * 16 + lo) * 2) =
                  f2bf(acc[p][n][rr] + (n ? bs1 : bs0));
          ushort8 v = *(const ushort8*)(rp_ + (lane >> 2) * 64 + (lane & 3) * 16);
          int hc = hcb + (lane & 3) * 8;
          int gm = m0 + p * 16 + (lane >> 2);
          *(ushort8*)(dst + (((size_t)((gm >> 8) * 6 + (hc >> 6))) << 14) +
                      (gm & 255) * 64 + (hc & 63)) = v;
        }
      } else {
        // vT: chunk [32col][16m], 32B rows
#pragma unroll
        for (int p = 0; p < 4; ++p) {
#pragma unroll
          for (int n = 0; n < 2; ++n)
#pragma unroll
            for (int rr = 0; rr < 4; ++rr)
              *(u16*)(rp_ + (n * 16 + lo) * 32 + (hi * 4 + rr) * 2) =
                  f2bf(acc[p][n][rr] + (n ? bs1 : bs0));
          ushort8 v = *(const ushort8*)(rp_ + (lane >> 1) * 32 + (lane & 1) * 16);
          int hc = hcb + (lane >> 1);
          int tg = (m0 & 255) + p * 16 + (lane & 1) * 8;
          *(ushort8*)(dst + (((size_t)((m0 >> 8) * 6 + (hc >> 6))) << 14) +
                      (hc & 63) * 256 + tg) = v;
        }
      }
    } else {
      const int colb = t * 128 + wc * 32 + lo;
#pragma unroll
      for (int m = 0; m < 4; ++m)
#pragma unroll
        for (int rr = 0; rr < 4; ++rr) {
          int gm = m0 + m * 16 + hi * 4 + rr;
          __builtin_nontemporal_store(acc[m][0][rr] + bs0, &oF[(size_t)gm * 384 + colb]);
          __builtin_nontemporal_store(acc[m][1][rr] + bs1, &oF[(size_t)gm * 384 + colb + 16]);
        }
    }
  }
}

// ---------------- windowed causal attention (K and V^T staged via gl_lds) ----------------
__global__ __launch_bounds__(256) void attn_k(
    const u16* __restrict__ Qb, const u16* __restrict__ Kb,
    const u16* __restrict__ VTb, const float* __restrict__ gate,
    u16* __restrict__ Ao) {
  __shared__ u16 Ks[128 * 64];      // [key][d]   swizzled, 16KB
  __shared__ u16 Vs[64 * 128];      // [d][key]   swizzled, 16KB
  __shared__ u16 Ps[4][16 * 128];   // per-wave P [q][key] swizzled, 16KB
  const int bx = blockIdx.x;
  const int qt = bx & 3, bh = bx >> 2;
  const int h = bh % 6, b = bh / 6;
  const int i0 = qt * 64, j0 = i0 - 64;
  const int tid = threadIdx.x, w = tid >> 6, lane = tid & 63;
  const int lo = lane & 15, hi = lane >> 4;

  const u16* Kh = Kb + (size_t)bh * (256 * 64);
  const u16* Vh = VTb + (size_t)bh * (64 * 256);
  const u16* Qh = Qb + (size_t)bh * (256 * 64);

#pragma unroll
  for (int it = 0; it < 4; ++it) {
    int chunk = tid + it * 256;
    int row = chunk >> 3, cc = chunk & 7;
    int csrc = cc ^ (row & 7);
    int j = j0 + row; if (j < 0) j = 0;       // masked later via P=0
    gl_lds16(Kh + j * 64 + csrc * 8, Ks + chunk * 8);
  }
#pragma unroll
  for (int it = 0; it < 4; ++it) {
    int chunk = tid + it * 256;
    int d = chunk >> 4, kc = chunk & 15;
    int ksrc = kc ^ (d & 7);
    int j = j0 + ksrc * 8; if (j < 0) j = 0;  // whole-chunk invalid only
    gl_lds16(Vh + d * 256 + j, Vs + chunk * 8);
  }

  const int iq = i0 + w * 16 + lo;
  short8 aq0 = *(const short8*)(Qh + iq * 64 + hi * 8);
  short8 aq1 = *(const short8*)(Qh + iq * 64 + 32 + hi * 8);

  __syncthreads();

  const f32x4 Z4 = {0.f, 0.f, 0.f, 0.f};
  f32x4 accS[8];
#pragma unroll
  for (int t = 0; t < 8; ++t) accS[t] = Z4;
#pragma unroll
  for (int t = 0; t < 8; ++t) {
    int key = t * 16 + lo;
    int base = key * 128;
    int sw = (key & 7) << 4;
    short8 bk0 = *(const short8*)((const char*)Ks + ((base + hi * 16) ^ sw));
    short8 bk1 = *(const short8*)((const char*)Ks + ((base + 64 + hi * 16) ^ sw));
    accS[t] = __builtin_amdgcn_mfma_f32_16x16x32_bf16(aq0, bk0, accS[t], 0, 0, 0);
    accS[t] = __builtin_amdgcn_mfma_f32_16x16x32_bf16(aq1, bk1, accS[t], 0, 0, 0);
  }

  float pv[4][8];
  float rinv[4];
#pragma unroll
  for (int r = 0; r < 4; ++r) {
    int i = i0 + w * 16 + hi * 4 + r;
    float mx = -1e30f;
    float vals[8];
#pragma unroll
    for (int t = 0; t < 8; ++t) {
      int j = j0 + t * 16 + lo;
      float s = accS[t][r] * 0.125f;          // 1/sqrt(64)
      bool ok = (j >= 0) && (j <= i) && (j >= i - 64);
      vals[t] = ok ? s : -1e30f;
      mx = fmaxf(mx, vals[t]);
    }
#pragma unroll
    for (int off = 1; off < 16; off <<= 1) mx = fmaxf(mx, __shfl_xor(mx, off));
    float sum = 0.f;
#pragma unroll
    for (int t = 0; t < 8; ++t) {
      float p = __expf(vals[t] - mx);
      pv[r][t] = p;
      sum += p;
    }
#pragma unroll
    for (int off = 1; off < 16; off <<= 1) sum += __shfl_xor(sum, off);
    rinv[r] = 1.0f / sum;
  }

  u16* Pw = Ps[w];
#pragma unroll
  for (int r = 0; r < 4; ++r) {
    int ql = hi * 4 + r;
    int sw = (ql & 7) << 4;
#pragma unroll
    for (int t = 0; t < 8; ++t) {
      int off = (ql * 256 + (t * 16 + lo) * 2) ^ sw;
      *(u16*)((char*)Pw + off) = f2bf(pv[r][t]);
    }
  }

  f32x4 accO[4];
#pragma unroll
  for (int dt = 0; dt < 4; ++dt) accO[dt] = Z4;
#pragma unroll
  for (int ks = 0; ks < 4; ++ks) {
    int offA = (lo * 256 + ks * 64 + hi * 16) ^ ((lo & 7) << 4);
    short8 ap = *(const short8*)((const char*)Pw + offA);
#pragma unroll
    for (int dt = 0; dt < 4; ++dt) {
      int d = dt * 16 + lo;
      int offB = (d * 256 + ks * 64 + hi * 16) ^ ((d & 7) << 4);
      short8 bv = *(const short8*)((const char*)Vs + offB);
      accO[dt] = __builtin_amdgcn_mfma_f32_16x16x32_bf16(ap, bv, accO[dt], 0, 0, 0);
    }
  }

#pragma unroll
  for (int dt = 0; dt < 4; ++dt) {
    int d = dt * 16 + lo;
    float gg = gate[h * 64 + d];
#pragma unroll
    for (int r = 0; r < 4; ++r) {
      int i = i0 + w * 16 + hi * 4 + r;
      float v = accO[dt][r] * rinv[r] * gg;
      Ao[(size_t)(b * 256 + i) * 384 + h * 64 + d] = f2bf(v);
    }
  }
}

// ---------------- launch ----------------
extern "C" void kernel_launch(void* const* d_in, const int* in_sizes, int n_in,
                              void* d_out, int out_size, void* d_ws, size_t ws_size,
                              hipStream_t stream) {
  const float* x      = (const float*)d_in[0];
  const float* qkv_w  = (const float*)d_in[1];
  const float* qkv_b  = (const float*)d_in[2];
  const float* proj_w = (const float*)d_in[3];
  const float* proj_b = (const float*)d_in[4];
  const float* gate   = (const float*)d_in[5];
  float* out = (float*)d_out;

  // ws layout:
  //   [0, 50331648)            att (attention output, bf16)
  //   [50331648, 100663296)    vT [b,h,d,t] bf16
  //   [100663296, 101548032)   w1T [1152,384] bf16
  //   [101548032, 101842944)   pT  [384,384]  bf16
  char* ws = (char*)d_ws;
  u16* att  = (u16*)ws;
  u16* vT   = (u16*)(ws + 50331648);
  u16* w1T  = (u16*)(ws + 100663296);
  u16* pT   = (u16*)(ws + 101548032);
  u16* qbuf = (u16*)d_out;                         // d_out doubles as q+k scratch
  u16* kbuf = (u16*)((char*)d_out + 50331648);

  transpose_cvt_k<<<dim3(36, 12), dim3(32, 8), 0, stream>>>(qkv_w, w1T, 384, 1152);
  transpose_cvt_k<<<dim3(12, 12), dim3(32, 8), 0, stream>>>(proj_w, pT, 384, 384);

  gemm_k<1><<<1024, 256, 0, stream>>>(x, w1T, qkv_b, qbuf, kbuf, vT, nullptr);
  attn_k<<<256 * 6 * 4, 256, 0, stream>>>(qbuf, kbuf, vT, gate, att);
  gemm_k<2><<<1024, 256, 0, stream>>>(att, pT, proj_b, nullptr, nullptr, nullptr, out);
}

// Round 21
// 184.828 us; speedup vs baseline: 1.5319x; 1.0176x over previous
//
#include <hip/hip_runtime.h>
#include <hip/hip_bf16.h>

typedef unsigned short u16;
typedef __attribute__((ext_vector_type(8))) short short8;
typedef __attribute__((ext_vector_type(8))) unsigned short ushort8;
typedef __attribute__((ext_vector_type(4))) float f32x4;
typedef __attribute__((ext_vector_type(4))) float f4;

#define GLB_CAST(p) ((const __attribute__((address_space(1))) unsigned int*)(p))
#define LDS_CAST(p) ((__attribute__((address_space(3))) unsigned int*)(p))

__device__ __forceinline__ void gl_lds16(const void* g, void* l) {
  __builtin_amdgcn_global_load_lds(GLB_CAST(g), LDS_CAST(l), 16, 0, 0);
}

__device__ __forceinline__ u16 f2bf(float f) {
  __hip_bfloat16 b = __float2bfloat16(f);           // RNE
  return __builtin_bit_cast(u16, b);
}
__device__ __forceinline__ float bf2f(u16 u) {
  unsigned int x = ((unsigned int)u) << 16;
  return __builtin_bit_cast(float, x);
}

// ---------------- prep: W [R][C] f32 -> Wt [C][R] bf16 ----------------
__global__ void transpose_cvt_k(const float* __restrict__ in,
                                u16* __restrict__ out, int R, int C) {
  __shared__ float tile[32][33];
  int c0 = blockIdx.x * 32, r0 = blockIdx.y * 32;
  int tx = threadIdx.x, ty = threadIdx.y;     // 32 x 8
#pragma unroll
  for (int i = 0; i < 32; i += 8)
    tile[ty + i][tx] = in[(size_t)(r0 + ty + i) * C + c0 + tx];
  __syncthreads();
#pragma unroll
  for (int i = 0; i < 32; i += 8)
    out[(size_t)(c0 + ty + i) * R + r0 + tx] = f2bf(tile[tx][ty + i]);
}

// ========== R16 GEMM: NT A-stream loads; CACHED q/k/vT stores; NT final-out ==========
// Block 256 thr = 4 waves; wave owns 32 n-cols; A [64x384] resident LDS (48KB);
// per-wave-private B ring (3 x 2KB), depth-2 prefetch, counted vmcnt, no loop barriers.
// NT loads keep the 48MB read-stream out of L2 (B panel survives); q/k/vT stores
// CACHED (attn consumes them soon -> L2/L3 hits, stores write-combine); gemm2's
// final f32 out stays NT (full-line, never re-read on device).
// EPI=1: qkv -> q/k row-major [b,h,t,d] + vT [b,h,d,t] (bf16); NT=9.
// EPI=2: out = att@pT^T + bias -> f32 [M,384]; NT=3.
template <int EPI>
__global__ __launch_bounds__(256, 2) void gemm_k(
    const void* __restrict__ Av, const u16* __restrict__ Bt,
    const float* __restrict__ bias,
    u16* __restrict__ oQ, u16* __restrict__ oK, u16* __restrict__ oVT,
    float* __restrict__ oF) {
  constexpr int K = 384;
  constexpr int NT = (EPI == 1) ? 9 : 3;
  __shared__ u16 As[64 * 384];         // 48KB, swizzled rows of 768B
  __shared__ u16 Bs[4][3][1024];       // 24KB: per-wave 3 slots [32col][32k]
  __shared__ u16 Rs[4][512];           // 4KB: per-wave 1KB repack chunk
  __shared__ u16 bias_sh[NT * 128];    // bf16 bias

  const int tid = threadIdx.x;
  const int m0 = blockIdx.x * 64;
  const int lane = tid & 63, wid = tid >> 6;   // wid = wc (4 waves x 32 cols)
  const int lo = lane & 15, hi = lane >> 4;
  const int wc = wid;

  for (int i = tid; i < NT * 128; i += 256) bias_sh[i] = f2bf(bias[i]);

  // ---- B staging (CACHEABLE - must stay L2-resident) ----
  const int bcol = wc * 32 + (lane >> 2);
  const int bc = ((lane & 3) ^ ((lane >> 3) & 3)) * 8;   // source k-offset (elems)
  char* const slot_l = (char*)&Bs[0][0][0] + wid * 6144 + lane * 16;
  auto stageB = [&](int slot, int tn, int kt) {
    const u16* s = Bt + (size_t)(tn * 128 + bcol) * K + kt * 32 + bc;
    char* d = slot_l + slot * 2048;
    gl_lds16(s, d);
    gl_lds16(s + 16 * K, d + 1024);
  };

  stageB(0, 0, 0);
  stageB(1, 0, 1);

  // ---- A staged once (NON-TEMPORAL loads: stream must not evict B) ----
  if (EPI == 1) {
    const float* X = (const float*)Av;
#pragma unroll
    for (int i = 0; i < 12; ++i) {
      int c = tid + i * 256;           // 3072 chunks of 16B
      int row = c / 48, cc = c % 48;
      const float* src = X + (size_t)(m0 + row) * K + cc * 8;
      f4 a = __builtin_nontemporal_load((const f4*)src);
      f4 b = __builtin_nontemporal_load((const f4*)(src + 4));
      ushort8 o;
#pragma unroll
      for (int j = 0; j < 4; ++j) { o[j] = f2bf(a[j]); o[4 + j] = f2bf(b[j]); }
      *(ushort8*)((char*)As + row * 768 + ((cc * 16) ^ ((row & 7) << 4))) = o;
    }
  } else {
    const u16* Ab = (const u16*)Av;
#pragma unroll
    for (int i = 0; i < 12; ++i) {
      int c = tid + i * 256;
      int row = c / 48, cc = c % 48;
      ushort8 v = __builtin_nontemporal_load(
          (const ushort8*)(Ab + (size_t)(m0 + row) * K + cc * 8));
      *(ushort8*)((char*)As + row * 768 + ((cc * 16) ^ ((row & 7) << 4))) = v;
    }
  }
  __syncthreads();    // full drain (A ready, prologue B slots 0/1 ready)

  const int akey = (lo & 7) << 4;
  const int rk = ((lo >> 1) & 3) << 4;       // B read key
  int abase[4];
#pragma unroll
  for (int m = 0; m < 4; ++m) abase[m] = (m * 16 + lo) * 768;
  const int bbase = lo * 64 + (hi * 16 ^ rk);
  const char* const Asc = (const char*)As;
  const char* const sb0 = (const char*)&Bs[0][0][0] + wid * 6144;
  char* const rp_ = (char*)&Rs[0][0] + wid * 1024;

  const f32x4 Z4 = {0.f, 0.f, 0.f, 0.f};

  for (int t = 0; t < NT; ++t) {
    f32x4 acc[4][2];
#pragma unroll
    for (int m = 0; m < 4; ++m) { acc[m][0] = Z4; acc[m][1] = Z4; }

#pragma unroll
    for (int kt = 0; kt < 12; ++kt) {
      // per-wave counted wait: slot(kt) ready, depth-2 pipeline stays live.
      if (kt == 0) asm volatile("s_waitcnt vmcnt(4)" ::: "memory");
      else         asm volatile("s_waitcnt vmcnt(2)" ::: "memory");

      const char* sb = sb0 + (kt % 3) * 2048;
      short8 af[4], bf[2];
#pragma unroll
      for (int m = 0; m < 4; ++m)
        af[m] = *(const short8*)(Asc + abase[m] + ((kt * 64 + hi * 16) ^ akey));
      bf[0] = *(const short8*)(sb + bbase);
      bf[1] = *(const short8*)(sb + 1024 + bbase);

      if (kt < 10)           stageB((kt + 2) % 3, t, kt + 2);
      else if (t + 1 < NT)   stageB((kt + 2) % 3, t + 1, kt - 10);

      __builtin_amdgcn_s_setprio(1);
#pragma unroll
      for (int m = 0; m < 4; ++m) {
        acc[m][0] = __builtin_amdgcn_mfma_f32_16x16x32_bf16(af[m], bf[0], acc[m][0], 0, 0, 0);
        acc[m][1] = __builtin_amdgcn_mfma_f32_16x16x32_bf16(af[m], bf[1], acc[m][1], 0, 0, 0);
      }
      __builtin_amdgcn_s_setprio(0);
    }

    // ---- epilogue: wave-private LDS repack -> coalesced CACHED 16B stores ----
    float bs0 = bf2f(bias_sh[t * 128 + wc * 32 + lo]);
    float bs1 = bf2f(bias_sh[t * 128 + wc * 32 + 16 + lo]);

    if (EPI == 1) {
      const int r3 = t / 3;
      u16* dst = (r3 == 0) ? oQ : ((r3 == 1) ? oK : oVT);
      const int hcb = (t - r3 * 3) * 128 + wc * 32;     // wave's head-space col base
      if (r3 < 2) {
        // chunk [16m][32col], 64B rows
#pragma unroll
        for (int p = 0; p < 4; ++p) {
#pragma unroll
          for (int n = 0; n < 2; ++n)
#pragma unroll
            for (int rr = 0; rr < 4; ++rr)
              *(u16*)(rp_ + (hi * 4 + rr) * 64 + (n * 16 + lo) * 2) =
                  f2bf(acc[p][n][rr] + (n ? bs1 : bs0));
          ushort8 v = *(const ushort8*)(rp_ + (lane >> 2) * 64 + (lane & 3) * 16);
          int hc = hcb + (lane & 3) * 8;
          int gm = m0 + p * 16 + (lane >> 2);
          *(ushort8*)(dst + (((size_t)((gm >> 8) * 6 + (hc >> 6))) << 14) +
                      (gm & 255) * 64 + (hc & 63)) = v;
        }
      } else {
        // vT: chunk [32col][16m], 32B rows
#pragma unroll
        for (int p = 0; p < 4; ++p) {
#pragma unroll
          for (int n = 0; n < 2; ++n)
#pragma unroll
            for (int rr = 0; rr < 4; ++rr)
              *(u16*)(rp_ + (n * 16 + lo) * 32 + (hi * 4 + rr) * 2) =
                  f2bf(acc[p][n][rr] + (n ? bs1 : bs0));
          ushort8 v = *(const ushort8*)(rp_ + (lane >> 1) * 32 + (lane & 1) * 16);
          int hc = hcb + (lane >> 1);
          int tg = (m0 & 255) + p * 16 + (lane & 1) * 8;
          *(ushort8*)(dst + (((size_t)((m0 >> 8) * 6 + (hc >> 6))) << 14) +
                      (hc & 63) * 256 + tg) = v;
        }
      }
    } else {
      const int colb = t * 128 + wc * 32 + lo;
#pragma unroll
      for (int m = 0; m < 4; ++m)
#pragma unroll
        for (int rr = 0; rr < 4; ++rr) {
          int gm = m0 + m * 16 + hi * 4 + rr;
          __builtin_nontemporal_store(acc[m][0][rr] + bs0, &oF[(size_t)gm * 384 + colb]);
          __builtin_nontemporal_store(acc[m][1][rr] + bs1, &oF[(size_t)gm * 384 + colb + 16]);
        }
    }
  }
}

// ---------------- windowed causal attention (K and V^T staged via gl_lds) ----------------
// R21: XCD-bijective block swizzle (6144 = 8 x 768): all 4 query-tiles of a head
// (plus ~192 consecutive heads) run on ONE XCD -> K/V windows become L2 hits.
__global__ __launch_bounds__(256) void attn_k(
    const u16* __restrict__ Qb, const u16* __restrict__ Kb,
    const u16* __restrict__ VTb, const float* __restrict__ gate,
    u16* __restrict__ Ao) {
  __shared__ u16 Ks[128 * 64];      // [key][d]   swizzled, 16KB
  __shared__ u16 Vs[64 * 128];      // [d][key]   swizzled, 16KB
  __shared__ u16 Ps[4][16 * 128];   // per-wave P [q][key] swizzled, 16KB
  const int bxr = blockIdx.x;
  const int bx = (bxr & 7) * 768 + (bxr >> 3);   // XCD-chunked bijection (6144%8==0)
  const int qt = bx & 3, bh = bx >> 2;
  const int h = bh % 6, b = bh / 6;
  const int i0 = qt * 64, j0 = i0 - 64;
  const int tid = threadIdx.x, w = tid >> 6, lane = tid & 63;
  const int lo = lane & 15, hi = lane >> 4;

  const u16* Kh = Kb + (size_t)bh * (256 * 64);
  const u16* Vh = VTb + (size_t)bh * (64 * 256);
  const u16* Qh = Qb + (size_t)bh * (256 * 64);

#pragma unroll
  for (int it = 0; it < 4; ++it) {
    int chunk = tid + it * 256;
    int row = chunk >> 3, cc = chunk & 7;
    int csrc = cc ^ (row & 7);
    int j = j0 + row; if (j < 0) j = 0;       // masked later via P=0
    gl_lds16(Kh + j * 64 + csrc * 8, Ks + chunk * 8);
  }
#pragma unroll
  for (int it = 0; it < 4; ++it) {
    int chunk = tid + it * 256;
    int d = chunk >> 4, kc = chunk & 15;
    int ksrc = kc ^ (d & 7);
    int j = j0 + ksrc * 8; if (j < 0) j = 0;  // whole-chunk invalid only
    gl_lds16(Vh + d * 256 + j, Vs + chunk * 8);
  }

  const int iq = i0 + w * 16 + lo;
  short8 aq0 = *(const short8*)(Qh + iq * 64 + hi * 8);
  short8 aq1 = *(const short8*)(Qh + iq * 64 + 32 + hi * 8);

  __syncthreads();

  const f32x4 Z4 = {0.f, 0.f, 0.f, 0.f};
  f32x4 accS[8];
#pragma unroll
  for (int t = 0; t < 8; ++t) accS[t] = Z4;
#pragma unroll
  for (int t = 0; t < 8; ++t) {
    int key = t * 16 + lo;
    int base = key * 128;
    int sw = (key & 7) << 4;
    short8 bk0 = *(const short8*)((const char*)Ks + ((base + hi * 16) ^ sw));
    short8 bk1 = *(const short8*)((const char*)Ks + ((base + 64 + hi * 16) ^ sw));
    accS[t] = __builtin_amdgcn_mfma_f32_16x16x32_bf16(aq0, bk0, accS[t], 0, 0, 0);
    accS[t] = __builtin_amdgcn_mfma_f32_16x16x32_bf16(aq1, bk1, accS[t], 0, 0, 0);
  }

  float pv[4][8];
  float rinv[4];
#pragma unroll
  for (int r = 0; r < 4; ++r) {
    int i = i0 + w * 16 + hi * 4 + r;
    float mx = -1e30f;
    float vals[8];
#pragma unroll
    for (int t = 0; t < 8; ++t) {
      int j = j0 + t * 16 + lo;
      float s = accS[t][r] * 0.125f;          // 1/sqrt(64)
      bool ok = (j >= 0) && (j <= i) && (j >= i - 64);
      vals[t] = ok ? s : -1e30f;
      mx = fmaxf(mx, vals[t]);
    }
#pragma unroll
    for (int off = 1; off < 16; off <<= 1) mx = fmaxf(mx, __shfl_xor(mx, off));
    float sum = 0.f;
#pragma unroll
    for (int t = 0; t < 8; ++t) {
      float p = __expf(vals[t] - mx);
      pv[r][t] = p;
      sum += p;
    }
#pragma unroll
    for (int off = 1; off < 16; off <<= 1) sum += __shfl_xor(sum, off);
    rinv[r] = 1.0f / sum;
  }

  u16* Pw = Ps[w];
#pragma unroll
  for (int r = 0; r < 4; ++r) {
    int ql = hi * 4 + r;
    int sw = (ql & 7) << 4;
#pragma unroll
    for (int t = 0; t < 8; ++t) {
      int off = (ql * 256 + (t * 16 + lo) * 2) ^ sw;
      *(u16*)((char*)Pw + off) = f2bf(pv[r][t]);
    }
  }

  f32x4 accO[4];
#pragma unroll
  for (int dt = 0; dt < 4; ++dt) accO[dt] = Z4;
#pragma unroll
  for (int ks = 0; ks < 4; ++ks) {
    int offA = (lo * 256 + ks * 64 + hi * 16) ^ ((lo & 7) << 4);
    short8 ap = *(const short8*)((const char*)Pw + offA);
#pragma unroll
    for (int dt = 0; dt < 4; ++dt) {
      int d = dt * 16 + lo;
      int offB = (d * 256 + ks * 64 + hi * 16) ^ ((d & 7) << 4);
      short8 bv = *(const short8*)((const char*)Vs + offB);
      accO[dt] = __builtin_amdgcn_mfma_f32_16x16x32_bf16(ap, bv, accO[dt], 0, 0, 0);
    }
  }

#pragma unroll
  for (int dt = 0; dt < 4; ++dt) {
    int d = dt * 16 + lo;
    float gg = gate[h * 64 + d];
#pragma unroll
    for (int r = 0; r < 4; ++r) {
      int i = i0 + w * 16 + hi * 4 + r;
      float v = accO[dt][r] * rinv[r] * gg;
      Ao[(size_t)(b * 256 + i) * 384 + h * 64 + d] = f2bf(v);
    }
  }
}

// ---------------- launch ----------------
extern "C" void kernel_launch(void* const* d_in, const int* in_sizes, int n_in,
                              void* d_out, int out_size, void* d_ws, size_t ws_size,
                              hipStream_t stream) {
  const float* x      = (const float*)d_in[0];
  const float* qkv_w  = (const float*)d_in[1];
  const float* qkv_b  = (const float*)d_in[2];
  const float* proj_w = (const float*)d_in[3];
  const float* proj_b = (const float*)d_in[4];
  const float* gate   = (const float*)d_in[5];
  float* out = (float*)d_out;

  // ws layout:
  //   [0, 50331648)            att (attention output, bf16)
  //   [50331648, 100663296)    vT [b,h,d,t] bf16
  //   [100663296, 101548032)   w1T [1152,384] bf16
  //   [101548032, 101842944)   pT  [384,384]  bf16
  char* ws = (char*)d_ws;
  u16* att  = (u16*)ws;
  u16* vT   = (u16*)(ws + 50331648);
  u16* w1T  = (u16*)(ws + 100663296);
  u16* pT   = (u16*)(ws + 101548032);
  u16* qbuf = (u16*)d_out;                         // d_out doubles as q+k scratch
  u16* kbuf = (u16*)((char*)d_out + 50331648);

  transpose_cvt_k<<<dim3(36, 12), dim3(32, 8), 0, stream>>>(qkv_w, w1T, 384, 1152);
  transpose_cvt_k<<<dim3(12, 12), dim3(32, 8), 0, stream>>>(proj_w, pT, 384, 384);

  gemm_k<1><<<1024, 256, 0, stream>>>(x, w1T, qkv_b, qbuf, kbuf, vT, nullptr);
  attn_k<<<256 * 6 * 4, 256, 0, stream>>>(qbuf, kbuf, vT, gate, att);
  gemm_k<2><<<1024, 256, 0, stream>>>(att, pT, proj_b, nullptr, nullptr, nullptr, out);
}